// Round 1
// baseline (327.993 us; speedup 1.0000x reference)
//
#include <hip/hip_runtime.h>
#include <stdint.h>

// FluteLinear: out[m,n] = sum_k x[m,k] * tables[qweight[n,k]] * scales[n, k/128]
// M=16, N=14336, K=4096, GROUP=128 (G=32). HBM-bound: qweight = 235 MB int32.
//
// Round-3 theory: flute_main's scattered 64x16B q-loads (2 instrs per 128B
// line, 16-row scatter per instr) cap the q stream at ~2.2 TB/s vs the
// ~6.7 TB/s the harness fill kernel sustains with contiguous bursts on the
// same chip. This version stages q via global_load_lds (each instruction a
// single contiguous 1 KB burst = the fill-kernel access pattern), with the
// XOR swizzle (col ^= (row&7)<<4) applied to the *global source* address
// (gload_lds dest must stay lane-linear, m104/m173) so the ds_read_b128
// fragment reads are bank-conflict-free (8 consecutive lanes tile all 32
// banks). One 256-k chunk (2 scale groups) per wave, 2 stage->compute phases
// reusing one wave-private 8 KB buffer (vmcnt(0) before reads, lgkmcnt(0)
// before re-stage; no barriers needed). LDS 36 KB/block -> 4 blocks/CU =
// 16 waves/CU, each parking 8 KB in flight while waiting. x is pre-converted
// to f16 once (xcast) so the hot loop has q-only HBM VMEM and no cvt chains.
//
// Predicted: flute_main ~105 -> ~50 us (hbm_gbps 2.2 -> ~4.5-5 TB/s),
// total 317.7 -> ~235 us. FETCH unchanged ~235 MB (rate problem, not
// over-fetch). If flat: granularity hypothesis wrong -> pull flute_main's
// own counter row next round before editing further.

#define K_DIM     4096
#define N_OUT     14336
#define G_CNT     32
#define NSL       16                 // partial slices: 16 chunks of 256 k
#define OUT_ELEMS (16 * 14336)
#define XH_OFF    ((size_t)NSL * OUT_ELEMS)   // float offset of f16-x in ws

typedef _Float16 f16x8 __attribute__((ext_vector_type(8)));
typedef _Float16 f16x4 __attribute__((ext_vector_type(4)));
typedef float    f32x4 __attribute__((ext_vector_type(4)));

union H2U { uint16_t u; _Float16 h; };
union B16 { uint32_t u[4]; f16x8 v; };

typedef const __attribute__((address_space(1))) uint32_t glb_u32;
typedef __attribute__((address_space(3)))       uint32_t lds_u32;

// ---- x f32 -> f16 (once per iteration, 256 KB -> 128 KB) ----
__global__ __launch_bounds__(256)
void xcast(const float4* __restrict__ x, f16x4* __restrict__ xh) {
    const int i = blockIdx.x * 256 + threadIdx.x;   // 16384 threads x 4 floats
    const float4 v = x[i];
    f16x4 h;
    h[0] = (_Float16)v.x; h[1] = (_Float16)v.y;
    h[2] = (_Float16)v.z; h[3] = (_Float16)v.w;
    xh[i] = h;
}

template<int ATOMIC>
__global__ __launch_bounds__(256, 4)
void flute_main(const float*    __restrict__ xf,
                const _Float16* __restrict__ xh,
                const int*      __restrict__ qw,
                const float*    __restrict__ scales,
                const float*    __restrict__ tables,
                float*          __restrict__ ws) {
    // stage: 4 waves x 8 KB (16 q-rows x 512 B, XOR-swizzled image)
    __shared__ int4     stageBuf[4][512];
    // pair-table (f16(tables[c0]) | f16(tables[c1])<<16), 4-way bank-replicated
    __shared__ uint32_t tabr[1024];

    const int tid = threadIdx.x;
    {
        H2U lo, hi;
        lo.h = (_Float16)tables[tid & 15];
        hi.h = (_Float16)tables[tid >> 4];
        const uint32_t v = (uint32_t)lo.u | ((uint32_t)hi.u << 16);
        uint4 q4 = {v, v, v, v};
        *(uint4*)(tabr + tid * 4) = q4;          // one ds_write_b128
    }
    __syncthreads();

    const int lane = tid & 63;
    const int wave = tid >> 6;
    const int t    = blockIdx.x * 4 + wave;      // 14336 wave-tasks
    const int kc   = t & 15;                     // 256-k chunk (2 scale groups)
    const int nt   = t >> 4;                     // 0..895
    const int n0   = nt << 4;

    const int col  = lane & 15;                  // n-offset (B,D) / m (A)
    const int quad = lane >> 4;                  // k-slot

    // ---- fragment-read addresses (swizzle applied on read) ----
    char* stW = (char*)&stageBuf[wave][0];
    const int swzr = (lane & 7) << 4;
    const int qsw  = (quad * 32) ^ swzr;
    const int ad0  = col * 512 + qsw;            // first 16B of lane's 8 codes
    const int ad1  = col * 512 + (qsw ^ 16);     // second 16B
    const int lr   = lane & 3;

    // ---- staging source: lane-linear 1 KB bursts, inverse-swizzled ----
    // LDS lin offset o = j*1024 + lane*16 -> row = 2j + (lane>>5), c = o&511.
    // Invariant: LDS[row][c] holds G[row][c ^ ((row&7)<<4)].
    const int hl    = lane >> 5;                 // which row of instr j's pair
    const int clh   = ((lane & 31) << 4) ^ (hl << 4);
    const int hlrow = hl << 14;                  // hl * 16384 (q row stride)
    const char* qb0 = (const char*)qw + (size_t)n0 * (K_DIM * 4) + kc * 1024;

    const int    n  = n0 + col;
    const float2 sc = *(const float2*)(scales + (size_t)n * G_CNT + kc * 2);

    const _Float16* xp  = xh + (size_t)col * K_DIM + kc * 256 + quad * 8;
    const float*    xpf = xf + (size_t)col * K_DIM + kc * 256 + quad * 8;

    f32x4 acc = {0.f, 0.f, 0.f, 0.f};

    #pragma unroll
    for (int p = 0; p < 2; ++p) {
        const char* qb = qb0 + p * 512;
        // 8 x global_load_lds dwordx4: each one contiguous 1 KB burst
        #pragma unroll
        for (int j = 0; j < 8; ++j) {
            const int c2j = ((2 * j) & 7) << 4;            // compile-time
            const int off = (j << 15) + hlrow + (clh ^ c2j);
            __builtin_amdgcn_global_load_lds((glb_u32*)(qb + off),
                                             (lds_u32*)(stW + (j << 10)),
                                             16, 0, 0);
        }
        // A fragments (f16 from L2-resident xh; f32+convert in fallback mode)
        f16x8 a[4];
        if constexpr (ATOMIC) {
            #pragma unroll
            for (int s = 0; s < 4; ++s) {
                const float4 lo = *(const float4*)(xpf + p * 128 + s * 32);
                const float4 hi = *(const float4*)(xpf + p * 128 + s * 32 + 4);
                f16x8 af;
                af[0] = (_Float16)lo.x; af[1] = (_Float16)lo.y;
                af[2] = (_Float16)lo.z; af[3] = (_Float16)lo.w;
                af[4] = (_Float16)hi.x; af[5] = (_Float16)hi.y;
                af[6] = (_Float16)hi.z; af[7] = (_Float16)hi.w;
                a[s] = af;
            }
        } else {
            #pragma unroll
            for (int s = 0; s < 4; ++s)
                a[s] = *(const f16x8*)(xp + p * 128 + s * 32);
        }
        // drain staging (wave-private buffer -> no barrier needed)
        asm volatile("s_waitcnt vmcnt(0)" ::: "memory");

        f32x4 tacc = {0.f, 0.f, 0.f, 0.f};
        #pragma unroll
        for (int s = 0; s < 4; ++s) {
            const int4 qa = *(const int4*)(stW + ad0 + s * 128);
            const int4 qc = *(const int4*)(stW + ad1 + s * 128);
            B16 bf;
            bf.u[0] = tabr[((qa.x + (qa.y << 4)) << 2) | lr];
            bf.u[1] = tabr[((qa.z + (qa.w << 4)) << 2) | lr];
            bf.u[2] = tabr[((qc.x + (qc.y << 4)) << 2) | lr];
            bf.u[3] = tabr[((qc.z + (qc.w << 4)) << 2) | lr];
            tacc = __builtin_amdgcn_mfma_f32_16x16x32_f16(a[s], bf.v, tacc, 0, 0, 0);
        }
        const float scp = p ? sc.y : sc.x;
        acc[0] += scp * tacc[0]; acc[1] += scp * tacc[1];
        acc[2] += scp * tacc[2]; acc[3] += scp * tacc[3];
        // before overwriting the stage buffer: all ds_reads must have landed
        if (p == 0) asm volatile("s_waitcnt lgkmcnt(0)" ::: "memory");
    }

    // D layout: col = lane&15 (= n-n0), row = quad*4 + r (= m)
    if constexpr (ATOMIC) {
        float* op = ws + n;                       // ws == out here
        #pragma unroll
        for (int r = 0; r < 4; ++r)
            atomicAdd(op + (size_t)(quad * 4 + r) * N_OUT, acc[r]);
    } else {
        float* op = ws + (size_t)kc * OUT_ELEMS + n;
        #pragma unroll
        for (int r = 0; r < 4; ++r)
            op[(size_t)(quad * 4 + r) * N_OUT] = acc[r];
    }
}

__global__ __launch_bounds__(256)
void flute_reduce(const float4* __restrict__ ws, float4* __restrict__ out) {
    const int i = blockIdx.x * 256 + threadIdx.x;   // 0..57343
    float4 s = ws[i];
    #pragma unroll
    for (int kc = 1; kc < NSL; ++kc) {
        const float4 u = ws[(size_t)kc * (OUT_ELEMS / 4) + i];
        s.x += u.x; s.y += u.y; s.z += u.z; s.w += u.w;
    }
    out[i] = s;
}

extern "C" void kernel_launch(void* const* d_in, const int* in_sizes, int n_in,
                              void* d_out, int out_size, void* d_ws, size_t ws_size,
                              hipStream_t stream) {
    const float* x      = (const float*)d_in[0];
    const int*   qw     = (const int*)  d_in[1];
    const float* scales = (const float*)d_in[2];
    const float* tables = (const float*)d_in[3];
    float*       out    = (float*)d_out;

    const size_t ws_needed = XH_OFF * sizeof(float) + (size_t)16 * K_DIM * sizeof(_Float16);
    dim3 block(256);

    if (ws_size >= ws_needed) {
        float*    ws = (float*)d_ws;
        _Float16* xh = (_Float16*)(ws + XH_OFF);
        xcast<<<dim3(64), block, 0, stream>>>((const float4*)x, (f16x4*)xh);
        flute_main<0><<<dim3(3584), block, 0, stream>>>(x, xh, qw, scales, tables, ws);
        flute_reduce<<<dim3(OUT_ELEMS / 4 / 256), block, 0, stream>>>(
            (const float4*)ws, (float4*)out);
    } else {
        // fallback: accumulate directly into out (needs zeroed out); xh unused
        hipMemsetAsync(out, 0, (size_t)out_size * sizeof(float), stream);
        flute_main<1><<<dim3(3584), block, 0, stream>>>(x, (const _Float16*)x,
                                                        qw, scales, tables, out);
    }
}